// Round 1
// baseline (87.266 us; speedup 1.0000x reference)
//
#include <hip/hip_runtime.h>
#include <hip/hip_fp16.h>

#define NQ 2048
#define NK 4096
#define DIMK 1024
#define HD 256          // 2*H*D_I
#define NBUCKET 257

typedef _Float16 h4 __attribute__((ext_vector_type(4)));
typedef float f4 __attribute__((ext_vector_type(4)));

// ---------------------------------------------------------------------------
// Kernel 1: fused f32->f16 conversion + projection GEMM  P = X @ W^T  (f16 out)
// Block tile 64(rows) x 64(cols), BK=64, 4 waves, mfma_f32_16x16x16f16.
// LDS rows XOR-swizzled (half-index ^= (row&7)<<3) -> conflict-free ds_read_b64.
// Grid.x = NQ/64 + NK/64 (q blocks then k blocks), grid.y = 256/64 = 4.
// ---------------------------------------------------------------------------
__global__ __launch_bounds__(256) void proj_kernel(
    const float* __restrict__ Xq, const float* __restrict__ Xk,
    const float* __restrict__ Wq, const float* __restrict__ Wk,
    _Float16* __restrict__ Pq, _Float16* __restrict__ Pk)
{
  __shared__ __align__(16) _Float16 xs[64 * 64];
  __shared__ __align__(16) _Float16 wsh[64 * 64];

  const int t = threadIdx.x;
  const int lane = t & 63;
  const int wave = t >> 6;
  const int bx = blockIdx.x;
  const bool isq = bx < (NQ / 64);
  const float* __restrict__ X = isq ? Xq : Xk;
  const float* __restrict__ W = isq ? Wq : Wk;
  _Float16* __restrict__ P = isq ? Pq : Pk;
  const int rb = (isq ? bx : bx - NQ / 64) * 64;
  const int cb = blockIdx.y * 64;
  const int r15 = lane & 15, g = lane >> 4;

  f4 acc[4];
#pragma unroll
  for (int i = 0; i < 4; ++i) acc[i] = (f4){0.f, 0.f, 0.f, 0.f};

  for (int kb = 0; kb < DIMK; kb += 64) {
    __syncthreads();  // protect LDS from previous iteration's readers
#pragma unroll
    for (int j = 0; j < 4; ++j) {
      int idx = t + j * 256;       // 0..1023
      int row = idx >> 4;          // 64 rows, 16 float4 chunks per row
      int c4 = idx & 15;
      f4 v = *(const f4*)(X + (size_t)(rb + row) * DIMK + kb + c4 * 4);
      h4 hv;
      hv[0] = (_Float16)v[0]; hv[1] = (_Float16)v[1];
      hv[2] = (_Float16)v[2]; hv[3] = (_Float16)v[3];
      *(h4*)&xs[row * 64 + ((c4 * 4) ^ ((row & 7) << 3))] = hv;
      f4 w = *(const f4*)(W + (size_t)(cb + row) * DIMK + kb + c4 * 4);
      h4 hw;
      hw[0] = (_Float16)w[0]; hw[1] = (_Float16)w[1];
      hw[2] = (_Float16)w[2]; hw[3] = (_Float16)w[3];
      *(h4*)&wsh[row * 64 + ((c4 * 4) ^ ((row & 7) << 3))] = hw;
    }
    __syncthreads();

    const int arow = wave * 16 + r15;   // this wave's 16-row strip
#pragma unroll
    for (int kc = 0; kc < 4; ++kc) {
      h4 a = *(const h4*)&xs[arow * 64 + ((kc * 16 + g * 4) ^ ((r15 & 7) << 3))];
#pragma unroll
      for (int cs = 0; cs < 4; ++cs) {
        int brow = cs * 16 + r15;
        h4 b = *(const h4*)&wsh[brow * 64 + ((kc * 16 + g * 4) ^ ((r15 & 7) << 3))];
        acc[cs] = __builtin_amdgcn_mfma_f32_16x16x16f16(a, b, acc[cs], 0, 0, 0);
      }
    }
  }

  // C/D layout: row = 4*(lane>>4)+i, col = lane&15  [measured m89]
#pragma unroll
  for (int cs = 0; cs < 4; ++cs)
#pragma unroll
    for (int i = 0; i < 4; ++i)
      P[(size_t)(rb + wave * 16 + g * 4 + i) * HD + cb + cs * 16 + r15] =
          (_Float16)acc[cs][i];
}

// ---------------------------------------------------------------------------
// Kernel 2: fused dot (8 heads, MFMA) + rpe + gate MLP + sigmoid + reduce.
// Block tile: 32 q-rows x 64 k-cols; 4 waves (2x2), each wave 16q x 32k.
// grid = (NK/64, NQ/32).
// ---------------------------------------------------------------------------
__global__ __launch_bounds__(256) void fused_kernel(
    const _Float16* __restrict__ qp, const _Float16* __restrict__ kp,
    const int* __restrict__ qpos, const int* __restrict__ kpos,
    const float* __restrict__ rpe, const float* __restrict__ gw1,
    const float* __restrict__ gb1, const float* __restrict__ gw2,
    const float* __restrict__ gb2, float* __restrict__ out)
{
  __shared__ __align__(16) _Float16 qlds[32 * 256];
  __shared__ __align__(16) _Float16 klds[64 * 256];
  __shared__ __align__(16) float rpel[NBUCKET * 4];
  __shared__ int qposl[32];
  __shared__ int kposl[64];

  const int t = threadIdx.x;
  const int lane = t & 63, wave = t >> 6;
  const int wq = wave >> 1, wk = wave & 1;
  const int qb = blockIdx.y * 32, kb = blockIdx.x * 64;
  const int r15 = lane & 15, g = lane >> 4;

  for (int i = t; i < NBUCKET * 4; i += 256) rpel[i] = rpe[i];
  if (t < 32) qposl[t] = qpos[qb + t];
  else if (t < 96) kposl[t - 32] = kpos[kb + t - 32];

  // stage qp tile: 32 rows x 256 halfs (512B/row), 16B chunks, swizzled
#pragma unroll
  for (int j = 0; j < 4; ++j) {
    int idx = t + j * 256;
    int row = idx >> 5, c = idx & 31;
    *(uint4*)&qlds[row * 256 + ((c * 8) ^ ((row & 7) << 3))] =
        *(const uint4*)(qp + (size_t)(qb + row) * HD + c * 8);
  }
  // stage kp tile: 64 rows
#pragma unroll
  for (int j = 0; j < 8; ++j) {
    int idx = t + j * 256;
    int row = idx >> 5, c = idx & 31;
    *(uint4*)&klds[row * 256 + ((c * 8) ^ ((row & 7) << 3))] =
        *(const uint4*)(kp + (size_t)(kb + row) * HD + c * 8);
  }
  __syncthreads();

  f4 acc[2][8];
#pragma unroll
  for (int s = 0; s < 2; ++s)
#pragma unroll
    for (int h = 0; h < 8; ++h) acc[s][h] = (f4){0.f, 0.f, 0.f, 0.f};

  const int qrow = wq * 16 + r15;
#pragma unroll
  for (int h = 0; h < 8; ++h) {
#pragma unroll
    for (int c = 0; c < 2; ++c) {
      int colh = h * 32 + c * 16 + g * 4;
      h4 a = *(const h4*)&qlds[qrow * 256 + (colh ^ ((r15 & 7) << 3))];
#pragma unroll
      for (int s = 0; s < 2; ++s) {
        int krow = wk * 32 + s * 16 + r15;
        h4 b = *(const h4*)&klds[krow * 256 + (colh ^ ((r15 & 7) << 3))];
        acc[s][h] = __builtin_amdgcn_mfma_f32_16x16x16f16(a, b, acc[s][h], 0, 0, 0);
      }
    }
  }

  // gate weights: uniform loads (expect s_load / SGPR residency)
  float w1v[8][4], b1v[8], w2v[4][8], b2v[4];
#pragma unroll
  for (int e = 0; e < 8; ++e) {
    b1v[e] = gb1[e];
#pragma unroll
    for (int h = 0; h < 4; ++h) w1v[e][h] = gw1[e * 4 + h];
  }
#pragma unroll
  for (int h = 0; h < 4; ++h) {
    b2v[h] = gb2[h];
#pragma unroll
    for (int e = 0; e < 8; ++e) w2v[h][e] = gw2[h * 8 + e];
  }

#pragma unroll
  for (int s = 0; s < 2; ++s) {
    const int kl = wk * 32 + s * 16 + r15;
    const int kpv = kposl[kl];
#pragma unroll
    for (int i = 0; i < 4; ++i) {
      const int ql = wq * 16 + g * 4 + i;
      int rel = qposl[ql] - kpv;
      int bidx = rel < -128 ? -128 : (rel > 128 ? 128 : rel);
      bidx += 128;
      f4 rp = *(const f4*)&rpel[bidx * 4];

      float sd[4], gi[4];
#pragma unroll
      for (int h = 0; h < 4; ++h) {
        sd[h] = fmaxf(acc[s][h][i] + rp[h], 0.0f);      // relu(dot_data + rpe)
        gi[h] = acc[s][4 + h][i] + rp[h];               // dot_gate + rpe
      }
      float gs[4];
#pragma unroll
      for (int h = 0; h < 4; ++h) gs[h] = b2v[h];
#pragma unroll
      for (int e = 0; e < 8; ++e) {
        float he = b1v[e];
#pragma unroll
        for (int h = 0; h < 4; ++h) he += gi[h] * w1v[e][h];
        he = fmaxf(he, 0.0f);
#pragma unroll
        for (int h = 0; h < 4; ++h) gs[h] += he * w2v[h][e];
      }
      float ov = 0.0f;
#pragma unroll
      for (int h = 0; h < 4; ++h) {
        float sg = __builtin_amdgcn_rcpf(1.0f + __expf(-gs[h]));
        ov += sd[h] * sg;
      }
      out[(size_t)(qb + ql) * NK + kb + kl] = ov;
    }
  }
}

// ---------------------------------------------------------------------------
extern "C" void kernel_launch(void* const* d_in, const int* in_sizes, int n_in,
                              void* d_out, int out_size, void* d_ws, size_t ws_size,
                              hipStream_t stream) {
  const float* Xq  = (const float*)d_in[0];
  const float* Xk  = (const float*)d_in[1];
  const int*   qpos = (const int*)d_in[2];
  const int*   kpos = (const int*)d_in[3];
  const float* Wq  = (const float*)d_in[4];
  const float* Wk  = (const float*)d_in[5];
  const float* rpe = (const float*)d_in[6];
  const float* gw1 = (const float*)d_in[7];
  const float* gb1 = (const float*)d_in[8];
  const float* gw2 = (const float*)d_in[9];
  const float* gb2 = (const float*)d_in[10];
  float* out = (float*)d_out;

  _Float16* qpf = (_Float16*)d_ws;                 // 2048*256 f16 = 1 MB
  _Float16* kpf = qpf + (size_t)NQ * HD;           // 4096*256 f16 = 2 MB

  proj_kernel<<<dim3(NQ / 64 + NK / 64, 4), 256, 0, stream>>>(
      Xq, Xk, Wq, Wk, qpf, kpf);
  fused_kernel<<<dim3(NK / 64, NQ / 32), 256, 0, stream>>>(
      qpf, kpf, qpos, kpos, rpe, gw1, gb1, gw2, gb2, out);
}

// Round 2
// 57.975 us; speedup vs baseline: 1.5052x; 1.5052x over previous
//
#include <hip/hip_runtime.h>
#include <hip/hip_fp16.h>

#define NQ 2048
#define NK 4096
#define DIMK 1024
#define HD 256          // 2*H*D_I
#define NBUCKET 257

typedef _Float16 h4 __attribute__((ext_vector_type(4)));
typedef float f4 __attribute__((ext_vector_type(4)));

// async global->LDS, 16B per lane (size must be a literal)
#define GLDS16(gp, lp)                                              \
  __builtin_amdgcn_global_load_lds(                                 \
      (const __attribute__((address_space(1))) void*)(gp),          \
      (__attribute__((address_space(3))) void*)(lp), 16, 0, 0)

// ---------------------------------------------------------------------------
// Kernel 1: fused f32->f16 projection GEMM  P = X @ W^T  (f16 out)
// Block tile 32(rows) x 64(cols), BK=64, 4 waves (2q x 2k), mfma 16x16x16 f16.
// f32 tiles staged via global_load_lds (double-buffered); conversion to f16
// happens at fragment-read time. Bank conflicts: source-side XOR swizzle of
// 16B chunks (chunk ^= row&7), LDS linear, same XOR applied on ds_read.
// Grid.x = NQ/32 + NK/32 = 192 (q blocks then k blocks), grid.y = 4.
// ---------------------------------------------------------------------------
__global__ __launch_bounds__(256) void proj_kernel(
    const float* __restrict__ Xq, const float* __restrict__ Xk,
    const float* __restrict__ Wq, const float* __restrict__ Wk,
    _Float16* __restrict__ Pq, _Float16* __restrict__ Pk)
{
  __shared__ __align__(16) float xs[2][32 * 64];   // 2 x 8 KB
  __shared__ __align__(16) float wsh[2][64 * 64];  // 2 x 16 KB  -> 48 KB total

  const int t = threadIdx.x;
  const int lane = t & 63;
  const int wave = t >> 6;
  const int bx = blockIdx.x;
  const bool isq = bx < (NQ / 32);
  const float* __restrict__ X = isq ? Xq : Xk;
  const float* __restrict__ W = isq ? Wq : Wk;
  _Float16* __restrict__ P = isq ? Pq : Pk;
  const int rb = (isq ? bx : bx - NQ / 32) * 32;
  const int cb = blockIdx.y * 64;
  const int r15 = lane & 15, g = lane >> 4;
  const int wq = wave >> 1, wk = wave & 1;
  const int c4 = t & 15;  // this thread's 16B chunk within a 64-float row

  f4 acc[2];
  acc[0] = (f4){0.f, 0.f, 0.f, 0.f};
  acc[1] = (f4){0.f, 0.f, 0.f, 0.f};

  // stage one K-tile (X: 2 calls, W: 4 calls; each call = 256 lanes x 16B)
  auto stage = [&](int buf, int kb) {
#pragma unroll
    for (int c = 0; c < 2; ++c) {
      int flat = c * 1024 + t * 4;          // float index in 32x64 tile
      int row = flat >> 6;
      int gc = c4 ^ (row & 7);              // pre-swizzled source chunk
      GLDS16(X + (size_t)(rb + row) * DIMK + kb + gc * 4, &xs[buf][flat]);
    }
#pragma unroll
    for (int c = 0; c < 4; ++c) {
      int flat = c * 1024 + t * 4;          // float index in 64x64 tile
      int row = flat >> 6;
      int gc = c4 ^ (row & 7);
      GLDS16(W + (size_t)(cb + row) * DIMK + kb + gc * 4, &wsh[buf][flat]);
    }
  };

  auto compute = [&](int buf) {
    const int arow = wq * 16 + r15;
#pragma unroll
    for (int kc = 0; kc < 4; ++kc) {
      int k4 = kc * 4 + g;                  // 16B chunk holding this frag's 4 halves
      f4 af = *(const f4*)&xs[buf][arow * 64 + ((k4 ^ (arow & 7)) << 2)];
      h4 a;
      a[0] = (_Float16)af[0]; a[1] = (_Float16)af[1];
      a[2] = (_Float16)af[2]; a[3] = (_Float16)af[3];
#pragma unroll
      for (int cs = 0; cs < 2; ++cs) {
        int brow = wk * 32 + cs * 16 + r15;
        f4 bf = *(const f4*)&wsh[buf][brow * 64 + ((k4 ^ (brow & 7)) << 2)];
        h4 b;
        b[0] = (_Float16)bf[0]; b[1] = (_Float16)bf[1];
        b[2] = (_Float16)bf[2]; b[3] = (_Float16)bf[3];
        acc[cs] = __builtin_amdgcn_mfma_f32_16x16x16f16(a, b, acc[cs], 0, 0, 0);
      }
    }
  };

  // 2-phase schedule: STAGE(next) -> compute(cur) -> syncthreads (drains vmcnt)
  stage(0, 0);
  __syncthreads();
  int buf = 0;
  for (int tt = 0; tt < DIMK / 64; ++tt) {
    if (tt + 1 < DIMK / 64) stage(buf ^ 1, (tt + 1) * 64);
    compute(buf);
    __syncthreads();
    buf ^= 1;
  }

  // C/D layout: row = 4*(lane>>4)+i, col = lane&15  [measured m89]
#pragma unroll
  for (int cs = 0; cs < 2; ++cs)
#pragma unroll
    for (int i = 0; i < 4; ++i)
      P[(size_t)(rb + wq * 16 + g * 4 + i) * HD + cb + wk * 32 + cs * 16 + r15] =
          (_Float16)acc[cs][i];
}

// ---------------------------------------------------------------------------
// Kernel 2: fused dot (8 heads, MFMA) + rpe + gate MLP + sigmoid + reduce.
// Block tile: 32 q-rows x 64 k-cols; 4 waves (2x2), each wave 16q x 32k.
// grid = (NK/64, NQ/32).   (unchanged this round)
// ---------------------------------------------------------------------------
__global__ __launch_bounds__(256) void fused_kernel(
    const _Float16* __restrict__ qp, const _Float16* __restrict__ kp,
    const int* __restrict__ qpos, const int* __restrict__ kpos,
    const float* __restrict__ rpe, const float* __restrict__ gw1,
    const float* __restrict__ gb1, const float* __restrict__ gw2,
    const float* __restrict__ gb2, float* __restrict__ out)
{
  __shared__ __align__(16) _Float16 qlds[32 * 256];
  __shared__ __align__(16) _Float16 klds[64 * 256];
  __shared__ __align__(16) float rpel[NBUCKET * 4];
  __shared__ int qposl[32];
  __shared__ int kposl[64];

  const int t = threadIdx.x;
  const int lane = t & 63, wave = t >> 6;
  const int wq = wave >> 1, wk = wave & 1;
  const int qb = blockIdx.y * 32, kb = blockIdx.x * 64;
  const int r15 = lane & 15, g = lane >> 4;

  for (int i = t; i < NBUCKET * 4; i += 256) rpel[i] = rpe[i];
  if (t < 32) qposl[t] = qpos[qb + t];
  else if (t < 96) kposl[t - 32] = kpos[kb + t - 32];

  // stage qp tile: 32 rows x 256 halfs (512B/row), 16B chunks, swizzled
#pragma unroll
  for (int j = 0; j < 4; ++j) {
    int idx = t + j * 256;
    int row = idx >> 5, c = idx & 31;
    *(uint4*)&qlds[row * 256 + ((c * 8) ^ ((row & 7) << 3))] =
        *(const uint4*)(qp + (size_t)(qb + row) * HD + c * 8);
  }
  // stage kp tile: 64 rows
#pragma unroll
  for (int j = 0; j < 8; ++j) {
    int idx = t + j * 256;
    int row = idx >> 5, c = idx & 31;
    *(uint4*)&klds[row * 256 + ((c * 8) ^ ((row & 7) << 3))] =
        *(const uint4*)(kp + (size_t)(kb + row) * HD + c * 8);
  }
  __syncthreads();

  f4 acc[2][8];
#pragma unroll
  for (int s = 0; s < 2; ++s)
#pragma unroll
    for (int h = 0; h < 8; ++h) acc[s][h] = (f4){0.f, 0.f, 0.f, 0.f};

  const int qrow = wq * 16 + r15;
#pragma unroll
  for (int h = 0; h < 8; ++h) {
#pragma unroll
    for (int c = 0; c < 2; ++c) {
      int colh = h * 32 + c * 16 + g * 4;
      h4 a = *(const h4*)&qlds[qrow * 256 + (colh ^ ((r15 & 7) << 3))];
#pragma unroll
      for (int s = 0; s < 2; ++s) {
        int krow = wk * 32 + s * 16 + r15;
        h4 b = *(const h4*)&klds[krow * 256 + (colh ^ ((r15 & 7) << 3))];
        acc[s][h] = __builtin_amdgcn_mfma_f32_16x16x16f16(a, b, acc[s][h], 0, 0, 0);
      }
    }
  }

  // gate weights: uniform loads (expect s_load / SGPR residency)
  float w1v[8][4], b1v[8], w2v[4][8], b2v[4];
#pragma unroll
  for (int e = 0; e < 8; ++e) {
    b1v[e] = gb1[e];
#pragma unroll
    for (int h = 0; h < 4; ++h) w1v[e][h] = gw1[e * 4 + h];
  }
#pragma unroll
  for (int h = 0; h < 4; ++h) {
    b2v[h] = gb2[h];
#pragma unroll
    for (int e = 0; e < 8; ++e) w2v[h][e] = gw2[h * 8 + e];
  }

#pragma unroll
  for (int s = 0; s < 2; ++s) {
    const int kl = wk * 32 + s * 16 + r15;
    const int kpv = kposl[kl];
#pragma unroll
    for (int i = 0; i < 4; ++i) {
      const int ql = wq * 16 + g * 4 + i;
      int rel = qposl[ql] - kpv;
      int bidx = rel < -128 ? -128 : (rel > 128 ? 128 : rel);
      bidx += 128;
      f4 rp = *(const f4*)&rpel[bidx * 4];

      float sd[4], gi[4];
#pragma unroll
      for (int h = 0; h < 4; ++h) {
        sd[h] = fmaxf(acc[s][h][i] + rp[h], 0.0f);      // relu(dot_data + rpe)
        gi[h] = acc[s][4 + h][i] + rp[h];               // dot_gate + rpe
      }
      float gs[4];
#pragma unroll
      for (int h = 0; h < 4; ++h) gs[h] = b2v[h];
#pragma unroll
      for (int e = 0; e < 8; ++e) {
        float he = b1v[e];
#pragma unroll
        for (int h = 0; h < 4; ++h) he += gi[h] * w1v[e][h];
        he = fmaxf(he, 0.0f);
#pragma unroll
        for (int h = 0; h < 4; ++h) gs[h] += he * w2v[h][e];
      }
      float ov = 0.0f;
#pragma unroll
      for (int h = 0; h < 4; ++h) {
        float sg = __builtin_amdgcn_rcpf(1.0f + __expf(-gs[h]));
        ov += sd[h] * sg;
      }
      out[(size_t)(qb + ql) * NK + kb + kl] = ov;
    }
  }
}

// ---------------------------------------------------------------------------
extern "C" void kernel_launch(void* const* d_in, const int* in_sizes, int n_in,
                              void* d_out, int out_size, void* d_ws, size_t ws_size,
                              hipStream_t stream) {
  const float* Xq  = (const float*)d_in[0];
  const float* Xk  = (const float*)d_in[1];
  const int*   qpos = (const int*)d_in[2];
  const int*   kpos = (const int*)d_in[3];
  const float* Wq  = (const float*)d_in[4];
  const float* Wk  = (const float*)d_in[5];
  const float* rpe = (const float*)d_in[6];
  const float* gw1 = (const float*)d_in[7];
  const float* gb1 = (const float*)d_in[8];
  const float* gw2 = (const float*)d_in[9];
  const float* gb2 = (const float*)d_in[10];
  float* out = (float*)d_out;

  _Float16* qpf = (_Float16*)d_ws;                 // 2048*256 f16 = 1 MB
  _Float16* kpf = qpf + (size_t)NQ * HD;           // 4096*256 f16 = 2 MB

  proj_kernel<<<dim3(NQ / 32 + NK / 32, 4), 256, 0, stream>>>(
      Xq, Xk, Wq, Wk, qpf, kpf);
  fused_kernel<<<dim3(NK / 64, NQ / 32), 256, 0, stream>>>(
      qpf, kpf, qpos, kpos, rpe, gw1, gb1, gw2, gb2, out);
}